// Round 5
// baseline (389.697 us; speedup 1.0000x reference)
//
#include <hip/hip_runtime.h>
#include <math.h>

#define ROW_N 512
#define N_ITERS 100
#define LAMBDA 10.0f
#define PAIRS_PER_WAVE 2

typedef float f2 __attribute__((ext_vector_type(2)));

__device__ __forceinline__ f2 splat(float s) { f2 r; r.x = s; r.y = s; return r; }
__device__ __forceinline__ f2 ffma(f2 a, f2 b, f2 c) {
    return __builtin_elementwise_fma(a, b, c);
}

// Precompute FISTA momentum coefficients coef[k] = (t_k - 1) / t_{k+1}.
__global__ void coef_kernel(float* __restrict__ coefs) {
    if (threadIdx.x == 0) {
        float t = 1.0f;
        for (int k = 0; k < N_ITERS; ++k) {
            float t_new = 0.5f * (1.0f + sqrtf(1.0f + 4.0f * t * t));
            coefs[k] = (t - 1.0f) / t_new;
            t = t_new;
        }
    }
}

// TWO rows per wave packed in float2 components (every stencil op a
// v_pk_*_f32); 8 elems/lane; TWO sequential row-pairs per wave so the grid
// is exactly 1024 blocks = 4 blocks/CU = 4 waves/SIMD: one residency round.
// waves_per_eu(4,4): occupancy >4/EU is worthless here, so give the register
// allocator the full 128-reg unified budget -> no AGPR shuttling.
template <bool USE_TABLE>
__global__ __launch_bounds__(256)
__attribute__((amdgpu_waves_per_eu(4, 4)))
void fista_kernel(
    const float* __restrict__ in, float* __restrict__ out,
    const float* __restrict__ coefs, int n_rows)
{
    const int wid  = (int)((blockIdx.x * 256u + threadIdx.x) >> 6);
    const int lane = (int)(threadIdx.x & 63u);
    const int n_pairs = (n_rows + 1) >> 1;

    const bool lane_lo = (lane == 0);
    const bool lane_hi = (lane == 63);

    const float A = 1.0f / (1.0f + 16.0f * LAMBDA);   // 2*step
    const float B = LAMBDA / (1.0f + 16.0f * LAMBDA); // 2*step*lam
    const float C = 1.0f - A;
    const f2 Cv = splat(C), Av = splat(A), Bn = splat(-B), M2 = splat(-2.0f);

    #pragma unroll 1
    for (int pp = 0; pp < PAIRS_PER_WAVE; ++pp) {
        const int pid = wid * PAIRS_PER_WAVE + pp;
        if (pid >= n_pairs) break;

        const int r0 = pid * 2;
        const int r1 = (r0 + 1 < n_rows) ? r0 + 1 : r0;
        const float* rowA = in + (size_t)r0 * ROW_N + lane * 8;
        const float* rowB = in + (size_t)r1 * ROW_N + lane * 8;

        f2 y[8], ay[8], x[8], z[8];
        {
            const float4 a0 = *(const float4*)(rowA);
            const float4 a1 = *(const float4*)(rowA + 4);
            const float4 b0 = *(const float4*)(rowB);
            const float4 b1 = *(const float4*)(rowB + 4);
            y[0].x = a0.x; y[1].x = a0.y; y[2].x = a0.z; y[3].x = a0.w;
            y[4].x = a1.x; y[5].x = a1.y; y[6].x = a1.z; y[7].x = a1.w;
            y[0].y = b0.x; y[1].y = b0.y; y[2].y = b0.z; y[3].y = b0.w;
            y[4].y = b1.x; y[5].y = b1.y; y[6].y = b1.z; y[7].y = b1.w;
        }

        #pragma unroll 1
        for (int pass = 0; pass < 2; ++pass) {
            #pragma unroll
            for (int i = 0; i < 8; ++i) {
                ay[i] = Av * y[i];
                f2 x0;  // proj(y) = clip(y,0,y)
                x0.x = fminf(fmaxf(y[i].x, 0.0f), y[i].x);
                x0.y = fminf(fmaxf(y[i].y, 0.0f), y[i].y);
                x[i] = x0;
                z[i] = x0;
            }

            // pipeline prologue: halo + coef for iteration 0
            f2 zm2, zm1, zp0, zp1;
            zm2.x = __shfl_up(z[6].x, 1);   zm2.y = __shfl_up(z[6].y, 1);
            zm1.x = __shfl_up(z[7].x, 1);   zm1.y = __shfl_up(z[7].y, 1);
            zp0.x = __shfl_down(z[0].x, 1); zp0.y = __shfl_down(z[0].y, 1);
            zp1.x = __shfl_down(z[1].x, 1); zp1.y = __shfl_down(z[1].y, 1);
            float coef, t = 1.0f;
            if (USE_TABLE) coef = coefs[0];
            else           coef = 0.0f;   // (t0-1)/t1 = 0

            #pragma unroll 2
            for (int it = 0; it < N_ITERS; ++it) {
                // dd[j] = d[8L-2+j] = v - 2*w + u (second difference)
                f2 dd[10];
                dd[0] = ffma(M2, zm1, zm2 + z[0]);
                dd[1] = ffma(M2, z[0], zm1 + z[1]);
                #pragma unroll
                for (int j = 2; j < 8; ++j)
                    dd[j] = ffma(M2, z[j - 1], z[j - 2] + z[j]);
                dd[8] = ffma(M2, z[7], z[6] + zp0);
                dd[9] = ffma(M2, zp0, z[7] + zp1);
                if (lane_lo) { dd[0] = splat(0.0f); dd[1] = splat(0.0f); }
                if (lane_hi) { dd[8] = splat(0.0f); dd[9] = splat(0.0f); }

                // prefetch next iteration's coef (uniform s_load)
                float coef_next;
                if (USE_TABLE) {
                    coef_next = coefs[it + 1 < N_ITERS ? it + 1 : 0];
                } else {
                    float t_new = 0.5f + sqrtf(fmaf(t, t, 0.25f));
                    coef_next = (t_new - 1.0f) / (0.5f + sqrtf(fmaf(t_new, t_new, 0.25f)));
                    t = t_new;
                }

                const f2 cfv = splat(coef);
                auto upd = [&](int i) {
                    f2 dtd = ffma(M2, dd[i + 1], dd[i] + dd[i + 2]);
                    f2 u = ffma(Cv, z[i], ay[i]);
                    u = ffma(Bn, dtd, u);
                    f2 xn;
                    xn.x = __builtin_amdgcn_fmed3f(u.x, 0.0f, y[i].x); // clip(u,0,y)
                    xn.y = __builtin_amdgcn_fmed3f(u.y, 0.0f, y[i].y);
                    z[i] = ffma(cfv, xn - x[i], xn);
                    x[i] = xn;
                };

                // 1) edge elements first (they feed next iteration's halo)
                upd(0); upd(1); upd(6); upd(7);

                // 2) issue next halo shuffles on fresh edge values
                f2 nzm2, nzm1, nzp0, nzp1;
                nzm2.x = __shfl_up(z[6].x, 1);   nzm2.y = __shfl_up(z[6].y, 1);
                nzm1.x = __shfl_up(z[7].x, 1);   nzm1.y = __shfl_up(z[7].y, 1);
                nzp0.x = __shfl_down(z[0].x, 1); nzp0.y = __shfl_down(z[0].y, 1);
                nzp1.x = __shfl_down(z[1].x, 1); nzp1.y = __shfl_down(z[1].y, 1);

                // 3) middle elements while shuffles are in flight
                upd(2); upd(3); upd(4); upd(5);

                zm2 = nzm2; zm1 = nzm1; zp0 = nzp0; zp1 = nzp1;
                coef = coef_next;
            }

            #pragma unroll
            for (int i = 0; i < 8; ++i) y[i] = x[i];  // pass 2: y = pass-1 x
        }

        float* orowA = out + (size_t)r0 * ROW_N + lane * 8;
        *(float4*)(orowA)     = make_float4(x[0].x, x[1].x, x[2].x, x[3].x);
        *(float4*)(orowA + 4) = make_float4(x[4].x, x[5].x, x[6].x, x[7].x);
        if (r1 > r0) {
            float* orowB = out + (size_t)r1 * ROW_N + lane * 8;
            *(float4*)(orowB)     = make_float4(x[0].y, x[1].y, x[2].y, x[3].y);
            *(float4*)(orowB + 4) = make_float4(x[4].y, x[5].y, x[6].y, x[7].y);
        }
    }
}

extern "C" void kernel_launch(void* const* d_in, const int* in_sizes, int n_in,
                              void* d_out, int out_size, void* d_ws, size_t ws_size,
                              hipStream_t stream) {
    const float* in = (const float*)d_in[0];
    float* out = (float*)d_out;

    const int total   = in_sizes[0];
    const int n_rows  = total / ROW_N;                       // 16384
    const int n_pairs = (n_rows + 1) >> 1;                   // 8192
    const int n_waves = (n_pairs + PAIRS_PER_WAVE - 1) / PAIRS_PER_WAVE; // 4096
    const int blocks  = (n_waves + 3) / 4;                   // 256 thr = 4 waves

    if (ws_size >= N_ITERS * sizeof(float)) {
        float* coefs = (float*)d_ws;
        coef_kernel<<<1, 64, 0, stream>>>(coefs);
        fista_kernel<true><<<blocks, 256, 0, stream>>>(in, out, coefs, n_rows);
    } else {
        fista_kernel<false><<<blocks, 256, 0, stream>>>(in, out, nullptr, n_rows);
    }
}

// Round 6
// 360.580 us; speedup vs baseline: 1.0807x; 1.0807x over previous
//
#include <hip/hip_runtime.h>
#include <math.h>

#define ROW_N 512
#define N_ITERS 100
#define LAMBDA 10.0f

typedef float f2 __attribute__((ext_vector_type(2)));

__device__ __forceinline__ f2 splat(float s) { f2 r; r.x = s; r.y = s; return r; }
__device__ __forceinline__ f2 ffma(f2 a, f2 b, f2 c) {
    return __builtin_elementwise_fma(a, b, c);
}

// Precompute FISTA momentum coefficients coef[k] = (t_k - 1) / t_{k+1}.
__global__ void coef_kernel(float* __restrict__ coefs) {
    if (threadIdx.x == 0) {
        float t = 1.0f;
        for (int k = 0; k < N_ITERS; ++k) {
            float t_new = 0.5f * (1.0f + sqrtf(1.0f + 4.0f * t * t));
            coefs[k] = (t - 1.0f) / t_new;
            t = t_new;
        }
    }
}

// TWO rows per wave packed in float2 components (v_pk_*_f32); 8 elems/lane;
// ONE row-pair per wave (R3's best config: 8192 waves, 2048 blocks).
// Iteration order 2..7,0,1 with on-demand dd (peak 6 live, no dd[10] array,
// no rotation copies): up-halo shuffles issue after upd(7) and are consumed
// at the NEXT iteration's dd0 (~96+ cyc slack); down-halo shuffles issue at
// iter end, consumed at next dd8 (huge slack). waves_per_eu(2,8): 256-reg
// budget so the allocator has no occupancy motive to squeeze arch VGPRs.
template <bool USE_TABLE>
__global__ __launch_bounds__(256)
__attribute__((amdgpu_waves_per_eu(2, 8)))
void fista_kernel(
    const float* __restrict__ in, float* __restrict__ out,
    const float* __restrict__ coefs, int n_rows)
{
    const int pid  = (int)((blockIdx.x * 256u + threadIdx.x) >> 6); // row pair
    const int lane = (int)(threadIdx.x & 63u);
    const int n_pairs = (n_rows + 1) >> 1;
    if (pid >= n_pairs) return;

    const bool lane_lo = (lane == 0);
    const bool lane_hi = (lane == 63);

    const int r0 = pid * 2;
    const int r1 = (r0 + 1 < n_rows) ? r0 + 1 : r0;
    const float* rowA = in + (size_t)r0 * ROW_N + lane * 8;
    const float* rowB = in + (size_t)r1 * ROW_N + lane * 8;

    const float A = 1.0f / (1.0f + 16.0f * LAMBDA);   // 2*step
    const float B = LAMBDA / (1.0f + 16.0f * LAMBDA); // 2*step*lam
    const float C = 1.0f - A;
    const f2 Cv = splat(C), Av = splat(A), Bn = splat(-B), M2 = splat(-2.0f);
    const f2 Z2 = splat(0.0f);

    f2 y[8], ay[8], x[8], z[8];
    {
        const float4 a0 = *(const float4*)(rowA);
        const float4 a1 = *(const float4*)(rowA + 4);
        const float4 b0 = *(const float4*)(rowB);
        const float4 b1 = *(const float4*)(rowB + 4);
        y[0].x = a0.x; y[1].x = a0.y; y[2].x = a0.z; y[3].x = a0.w;
        y[4].x = a1.x; y[5].x = a1.y; y[6].x = a1.z; y[7].x = a1.w;
        y[0].y = b0.x; y[1].y = b0.y; y[2].y = b0.z; y[3].y = b0.w;
        y[4].y = b1.x; y[5].y = b1.y; y[6].y = b1.z; y[7].y = b1.w;
    }

    #pragma unroll 1
    for (int pass = 0; pass < 2; ++pass) {
        #pragma unroll
        for (int i = 0; i < 8; ++i) {
            ay[i] = Av * y[i];
            f2 x0;  // proj(y) = clip(y,0,y)
            x0.x = fminf(fmaxf(y[i].x, 0.0f), y[i].x);
            x0.y = fminf(fmaxf(y[i].y, 0.0f), y[i].y);
            x[i] = x0;
            z[i] = x0;
        }

        // pipeline prologue: halo for iteration 0
        f2 zm2, zm1, zp0, zp1;
        zm2.x = __shfl_up(z[6].x, 1);   zm2.y = __shfl_up(z[6].y, 1);
        zm1.x = __shfl_up(z[7].x, 1);   zm1.y = __shfl_up(z[7].y, 1);
        zp0.x = __shfl_down(z[0].x, 1); zp0.y = __shfl_down(z[0].y, 1);
        zp1.x = __shfl_down(z[1].x, 1); zp1.y = __shfl_down(z[1].y, 1);
        float coef, t = 1.0f;
        if (USE_TABLE) coef = coefs[0];
        else           coef = 0.0f;   // (t0-1)/t1 = 0

        #pragma unroll 2
        for (int it = 0; it < N_ITERS; ++it) {
            // next iteration's coef (uniform s_load, off critical path)
            float coef_next;
            if (USE_TABLE) {
                coef_next = coefs[it + 1 < N_ITERS ? it + 1 : 0];
            } else {
                float t_new = 0.5f + sqrtf(fmaf(t, t, 0.25f));
                coef_next = (t_new - 1.0f) / (0.5f + sqrtf(fmaf(t_new, t_new, 0.25f)));
                t = t_new;
            }

            const f2 cf = splat(coef);
            // update element i given dtd inputs dd[i], dd[i+1], dd[i+2]
            auto upd = [&](int i, f2 da, f2 db, f2 dc) {
                f2 dtd = ffma(M2, db, da + dc);
                f2 u = ffma(Cv, z[i], ay[i]);
                u = ffma(Bn, dtd, u);
                f2 xn;
                xn.x = __builtin_amdgcn_fmed3f(u.x, 0.0f, y[i].x); // clip(u,0,y)
                xn.y = __builtin_amdgcn_fmed3f(u.y, 0.0f, y[i].y);
                z[i] = ffma(cf, xn - x[i], xn);
                x[i] = xn;
            };

            // interior dd from OLD z (dd2,dd3 stay live for upd(0),upd(1))
            f2 dd2 = ffma(M2, z[1], z[0] + z[2]);
            f2 dd3 = ffma(M2, z[2], z[1] + z[3]);
            f2 dd4 = ffma(M2, z[3], z[2] + z[4]);
            f2 dd5 = ffma(M2, z[4], z[3] + z[5]);
            f2 dd6 = ffma(M2, z[5], z[4] + z[6]);
            f2 dd7 = ffma(M2, z[6], z[5] + z[7]);

            upd(2, dd2, dd3, dd4);
            upd(3, dd3, dd4, dd5);
            upd(4, dd4, dd5, dd6);
            upd(5, dd5, dd6, dd7);

            // down-halo dd (z6,z7 still old); zp0/zp1 from prev iter's end
            f2 dd8 = ffma(M2, z[7], z[6] + zp0);
            f2 dd9 = ffma(M2, zp0, z[7] + zp1);
            if (lane_hi) { dd8 = Z2; dd9 = Z2; }  // d undefined past n-3

            upd(6, dd6, dd7, dd8);
            upd(7, dd7, dd8, dd9);

            // issue next iter's UP halo now (new z6,z7); consumed at next dd0
            f2 nzm2, nzm1;
            nzm2.x = __shfl_up(z[6].x, 1); nzm2.y = __shfl_up(z[6].y, 1);
            nzm1.x = __shfl_up(z[7].x, 1); nzm1.y = __shfl_up(z[7].y, 1);

            // up-halo dd (z0,z1 still old; zm2,zm1 are THIS iter's halo)
            f2 dd0 = ffma(M2, zm1, zm2 + z[0]);
            f2 dd1 = ffma(M2, z[0], zm1 + z[1]);
            if (lane_lo) { dd0 = Z2; dd1 = Z2; }  // d undefined below 0

            upd(0, dd0, dd1, dd2);
            upd(1, dd1, dd2, dd3);

            // issue next iter's DOWN halo (new z0,z1); consumed at next dd8
            zp0.x = __shfl_down(z[0].x, 1); zp0.y = __shfl_down(z[0].y, 1);
            zp1.x = __shfl_down(z[1].x, 1); zp1.y = __shfl_down(z[1].y, 1);

            zm2 = nzm2; zm1 = nzm1;  // renamed away by unroll-2
            coef = coef_next;
        }

        #pragma unroll
        for (int i = 0; i < 8; ++i) y[i] = x[i];  // pass 2: y = pass-1 x
    }

    float* orowA = out + (size_t)r0 * ROW_N + lane * 8;
    *(float4*)(orowA)     = make_float4(x[0].x, x[1].x, x[2].x, x[3].x);
    *(float4*)(orowA + 4) = make_float4(x[4].x, x[5].x, x[6].x, x[7].x);
    if (r1 > r0) {
        float* orowB = out + (size_t)r1 * ROW_N + lane * 8;
        *(float4*)(orowB)     = make_float4(x[0].y, x[1].y, x[2].y, x[3].y);
        *(float4*)(orowB + 4) = make_float4(x[4].y, x[5].y, x[6].y, x[7].y);
    }
}

extern "C" void kernel_launch(void* const* d_in, const int* in_sizes, int n_in,
                              void* d_out, int out_size, void* d_ws, size_t ws_size,
                              hipStream_t stream) {
    const float* in = (const float*)d_in[0];
    float* out = (float*)d_out;

    const int total   = in_sizes[0];
    const int n_rows  = total / ROW_N;          // 16384
    const int n_pairs = (n_rows + 1) >> 1;      // 8192 waves, 1 pair/wave
    const int waves_per_block = 4;              // 256 threads
    const int blocks = (n_pairs + waves_per_block - 1) / waves_per_block;

    if (ws_size >= N_ITERS * sizeof(float)) {
        float* coefs = (float*)d_ws;
        coef_kernel<<<1, 64, 0, stream>>>(coefs);
        fista_kernel<true><<<blocks, 256, 0, stream>>>(in, out, coefs, n_rows);
    } else {
        fista_kernel<false><<<blocks, 256, 0, stream>>>(in, out, nullptr, n_rows);
    }
}